// Round 4
// baseline (1058.432 us; speedup 1.0000x reference)
//
#include <hip/hip_runtime.h>
#include <hip/hip_bf16.h>

// CorotationalBeam2D: per-element 2D corotational beam forces + nodal scatter.
//
// R3: split into 3 kernels to ablate the throughput wall (gather requests vs
// atomic RMWs) and cut scattered-request count via packed per-node records.
//   K1 node pass : phys_disp, F_ext_nd, zero nodal, build pk1/pk2 packed recs
//   K2 elem pass : packed gathers + element outputs + 4-float contribs -> ws
//   K3 scatter   : conn + contribs -> 18M atomics (isolated for profiling)
// Exact identities used: f3=-f0, f4=-f1 => fgB0=-fgA0, fgB1=-fgA1.

typedef float f32x4 __attribute__((ext_vector_type(4)));
typedef int   i32x4 __attribute__((ext_vector_type(4)));

__device__ __forceinline__ void atomic_add_f32(float* p, float v) {
#if defined(__gfx90a__) || defined(__gfx940__) || defined(__gfx941__) || defined(__gfx942__) || defined(__gfx950__)
    unsafeAtomicAdd(p, v);   // hardware global_atomic_add_f32, device scope
#else
    atomicAdd(p, v);
#endif
}

// ---------------- K1: node pass (one thread per node) ----------------
__global__ void __launch_bounds__(256) beam_node_pack_kernel(
        const float* __restrict__ pred,
        const float* __restrict__ coords,
        const float* __restrict__ Fext,
        const float* __restrict__ u_c_p,
        const float* __restrict__ theta_c_p,
        const float* __restrict__ F_c_p,
        const float* __restrict__ M_c_p,
        float* __restrict__ nodal,
        float* __restrict__ Fext_nd,
        float* __restrict__ phys,
        f32x4* __restrict__ pk1,     // {cx, cz, p0, p1}
        float* __restrict__ pk2,     // {p2}
        int n_nodes) {
    int n = blockIdx.x * blockDim.x + threadIdx.x;
    if (n >= n_nodes) return;
    const float u_c = *u_c_p;
    const float theta_c = *theta_c_p;
    const float F_c = *F_c_p;
    const float M_c = *M_c_p;

    long b = 3L * n;
    float p0 = pred[b + 0], p1 = pred[b + 1], p2 = pred[b + 2];
    float f0 = Fext[b + 0], f1 = Fext[b + 1], f2 = Fext[b + 2];
    float cx = coords[b + 0];
    float cz = coords[b + 2];

    phys[b + 0] = p0 * u_c;
    phys[b + 1] = p1 * u_c;
    phys[b + 2] = p2 * theta_c;
    Fext_nd[b + 0] = f0 / F_c;
    Fext_nd[b + 1] = f1 / F_c;
    Fext_nd[b + 2] = f2 / M_c;
    nodal[b + 0] = 0.0f;
    nodal[b + 1] = 0.0f;
    nodal[b + 2] = 0.0f;

    f32x4 r; r[0] = cx; r[1] = cz; r[2] = p0; r[3] = p1;
    pk1[n] = r;
    pk2[n] = p2;
}

// ---------------- K2: element compute (4 elements/thread, no atomics) ----
__global__ void __launch_bounds__(256) beam_elem_compute_kernel(
        const f32x4* __restrict__ pk1,
        const float* __restrict__ pk2,
        const int*   __restrict__ conn,
        const float* __restrict__ prop_E,
        const float* __restrict__ prop_A,
        const float* __restrict__ prop_I,
        const float* __restrict__ u_c_p,
        const float* __restrict__ theta_c_p,
        const float* __restrict__ F_c_p,
        const float* __restrict__ M_c_p,
        float* __restrict__ N_e,
        float* __restrict__ M1_e,
        float* __restrict__ M2_e,
        float* __restrict__ V_e,
        float* __restrict__ l0_o,
        float* __restrict__ c_o,
        float* __restrict__ s_o,
        float* __restrict__ gx,      // contrib: fgA0  (fgB0 = -gx)
        float* __restrict__ gy,      // contrib: fgA1  (fgB1 = -gy)
        float* __restrict__ mA,      // contrib: f2
        float* __restrict__ mB,      // contrib: f5
        int n_elems) {
    const float u_c = *u_c_p;
    const float theta_c = *theta_c_p;
    const float F_c = *F_c_p;
    const float M_c = *M_c_p;

    long t = (long)blockIdx.x * blockDim.x + threadIdx.x;
    long base = t * 4;
    if (base >= n_elems) return;

    if (base + 4 <= n_elems) {
        i32x4 c01 = __builtin_nontemporal_load((const i32x4*)(conn + 2 * base));
        i32x4 c23 = __builtin_nontemporal_load((const i32x4*)(conn + 2 * base + 4));
        f32x4 vE = __builtin_nontemporal_load((const f32x4*)(prop_E + base));
        f32x4 vA = __builtin_nontemporal_load((const f32x4*)(prop_A + base));
        f32x4 vI = __builtin_nontemporal_load((const f32x4*)(prop_I + base));

        int nA[4] = {c01.x, c01.z, c23.x, c23.z};
        int nB[4] = {c01.y, c01.w, c23.y, c23.w};

        // gathers: 2 requests per node-touch, 4 per element
        f32x4 A1[4], B1[4];
        float A2[4], B2[4];
        #pragma unroll
        for (int k = 0; k < 4; ++k) {
            A1[k] = pk1[nA[k]];
            B1[k] = pk1[nB[k]];
            A2[k] = pk2[nA[k]];
            B2[k] = pk2[nB[k]];
        }

        f32x4 oN, oM1, oM2, oV, oL, oC, oS, ogx, ogy, omA, omB;

        #pragma unroll
        for (int k = 0; k < 4; ++k) {
            float dx0 = B1[k][0] - A1[k][0];
            float dz0 = B1[k][1] - A1[k][1];
            float l0 = sqrtf(dx0 * dx0 + dz0 * dz0);
            float c = dx0 / l0;
            float s = dz0 / l0;

            float E  = vE[k];
            float EA = E * vA[k];
            float EI = E * vI[k];

            float l0_2 = l0 * l0;
            float l0_3 = l0_2 * l0;
            float k_ax   = EA * u_c     / (F_c * l0);
            float k_bend = EI * theta_c / (M_c * l0);
            float k_sw   = EI * theta_c / (F_c * l0_2);
            float k_tr   = EI * u_c     / (F_c * l0_3);
            float k_mw   = EI * u_c     / (M_c * l0_2);

            float ua =  c * A1[k][2] + s * A1[k][3];
            float wa = -s * A1[k][2] + c * A1[k][3];
            float ta = -A2[k];
            float ub =  c * B1[k][2] + s * B1[k][3];
            float wb = -s * B1[k][2] + c * B1[k][3];
            float tb = -B2[k];

            float f0 = k_ax * (ua - ub);
            float f1 = 12.0f * k_tr * (wa - wb) + 6.0f * k_sw * (ta + tb);
            float f2 = 6.0f * k_mw * (wa - wb) + k_bend * (4.0f * ta + 2.0f * tb);
            float f5 = 6.0f * k_mw * (wa - wb) + k_bend * (2.0f * ta + 4.0f * tb);

            oN[k]  = -f0 * F_c;          // f3*F_c, f3 = -f0 exactly
            oM1[k] = f2 * M_c;
            oM2[k] = f5 * M_c;
            oV[k]  = -f1 * F_c;          // f4*F_c, f4 = -f1 exactly
            oL[k]  = l0;
            oC[k]  = c;
            oS[k]  = s;

            ogx[k] = c * f0 - s * f1;    // fgA0; fgB0 = -fgA0
            ogy[k] = s * f0 + c * f1;    // fgA1; fgB1 = -fgA1
            omA[k] = f2;
            omB[k] = f5;
        }

        __builtin_nontemporal_store(oN,  (f32x4*)(N_e  + base));
        __builtin_nontemporal_store(oM1, (f32x4*)(M1_e + base));
        __builtin_nontemporal_store(oM2, (f32x4*)(M2_e + base));
        __builtin_nontemporal_store(oV,  (f32x4*)(V_e  + base));
        __builtin_nontemporal_store(oL,  (f32x4*)(l0_o + base));
        __builtin_nontemporal_store(oC,  (f32x4*)(c_o  + base));
        __builtin_nontemporal_store(oS,  (f32x4*)(s_o  + base));
        __builtin_nontemporal_store(ogx, (f32x4*)(gx + base));
        __builtin_nontemporal_store(ogy, (f32x4*)(gy + base));
        __builtin_nontemporal_store(omA, (f32x4*)(mA + base));
        __builtin_nontemporal_store(omB, (f32x4*)(mB + base));
    } else {
        for (long e = base; e < n_elems; ++e) {
            int a = conn[2 * e + 0];
            int b = conn[2 * e + 1];
            f32x4 A1 = pk1[a], B1 = pk1[b];
            float A2 = pk2[a], B2 = pk2[b];
            float dx0 = B1[0] - A1[0];
            float dz0 = B1[1] - A1[1];
            float l0 = sqrtf(dx0 * dx0 + dz0 * dz0);
            float c = dx0 / l0;
            float s = dz0 / l0;
            float E  = prop_E[e];
            float EA = E * prop_A[e];
            float EI = E * prop_I[e];
            float l0_2 = l0 * l0;
            float l0_3 = l0_2 * l0;
            float k_ax   = EA * u_c     / (F_c * l0);
            float k_bend = EI * theta_c / (M_c * l0);
            float k_sw   = EI * theta_c / (F_c * l0_2);
            float k_tr   = EI * u_c     / (F_c * l0_3);
            float k_mw   = EI * u_c     / (M_c * l0_2);
            float ua =  c * A1[2] + s * A1[3];
            float wa = -s * A1[2] + c * A1[3];
            float ta = -A2;
            float ub =  c * B1[2] + s * B1[3];
            float wb = -s * B1[2] + c * B1[3];
            float tb = -B2;
            float f0 = k_ax * (ua - ub);
            float f1 = 12.0f * k_tr * (wa - wb) + 6.0f * k_sw * (ta + tb);
            float f2 = 6.0f * k_mw * (wa - wb) + k_bend * (4.0f * ta + 2.0f * tb);
            float f5 = 6.0f * k_mw * (wa - wb) + k_bend * (2.0f * ta + 4.0f * tb);
            N_e[e]  = -f0 * F_c;
            M1_e[e] = f2 * M_c;
            M2_e[e] = f5 * M_c;
            V_e[e]  = -f1 * F_c;
            l0_o[e] = l0;
            c_o[e]  = c;
            s_o[e]  = s;
            gx[e] = c * f0 - s * f1;
            gy[e] = s * f0 + c * f1;
            mA[e] = f2;
            mB[e] = f5;
        }
    }
}

// ---------------- K3: atomic scatter only ----------------
__global__ void __launch_bounds__(256) beam_scatter_kernel(
        const int*   __restrict__ conn,
        const float* __restrict__ gx,
        const float* __restrict__ gy,
        const float* __restrict__ mA,
        const float* __restrict__ mB,
        float* __restrict__ nodal,
        int n_elems) {
    long t = (long)blockIdx.x * blockDim.x + threadIdx.x;
    long base = t * 4;
    if (base >= n_elems) return;

    if (base + 4 <= n_elems) {
        i32x4 c01 = __builtin_nontemporal_load((const i32x4*)(conn + 2 * base));
        i32x4 c23 = __builtin_nontemporal_load((const i32x4*)(conn + 2 * base + 4));
        f32x4 vgx = __builtin_nontemporal_load((const f32x4*)(gx + base));
        f32x4 vgy = __builtin_nontemporal_load((const f32x4*)(gy + base));
        f32x4 vmA = __builtin_nontemporal_load((const f32x4*)(mA + base));
        f32x4 vmB = __builtin_nontemporal_load((const f32x4*)(mB + base));

        int nA[4] = {c01.x, c01.z, c23.x, c23.z};
        int nB[4] = {c01.y, c01.w, c23.y, c23.w};

        #pragma unroll
        for (int k = 0; k < 4; ++k) {
            float* pa = nodal + 3 * (long)nA[k];
            float* pb = nodal + 3 * (long)nB[k];
            atomic_add_f32(pa + 0,  vgx[k]);
            atomic_add_f32(pa + 1,  vgy[k]);
            atomic_add_f32(pa + 2,  vmA[k]);
            atomic_add_f32(pb + 0, -vgx[k]);
            atomic_add_f32(pb + 1, -vgy[k]);
            atomic_add_f32(pb + 2,  vmB[k]);
        }
    } else {
        for (long e = base; e < n_elems; ++e) {
            int a = conn[2 * e + 0];
            int b = conn[2 * e + 1];
            float* pa = nodal + 3 * (long)a;
            float* pb = nodal + 3 * (long)b;
            atomic_add_f32(pa + 0,  gx[e]);
            atomic_add_f32(pa + 1,  gy[e]);
            atomic_add_f32(pa + 2,  mA[e]);
            atomic_add_f32(pb + 0, -gx[e]);
            atomic_add_f32(pb + 1, -gy[e]);
            atomic_add_f32(pb + 2,  mB[e]);
        }
    }
}

// ---------------- Fallback (monolithic, R2 path) ----------------
__global__ void __launch_bounds__(256) beam_node_kernel(
        const float* __restrict__ pred,
        const float* __restrict__ Fext,
        const float* __restrict__ u_c_p,
        const float* __restrict__ theta_c_p,
        const float* __restrict__ F_c_p,
        const float* __restrict__ M_c_p,
        float* __restrict__ nodal,
        float* __restrict__ Fext_nd,
        float* __restrict__ phys,
        int n3) {
    const float u_c = *u_c_p;
    const float theta_c = *theta_c_p;
    const float F_c = *F_c_p;
    const float M_c = *M_c_p;
    long t = (long)blockIdx.x * blockDim.x + threadIdx.x;
    long base = t * 4;
    if (base + 4 <= n3) {
        f32x4 p = __builtin_nontemporal_load((const f32x4*)(pred + base));
        f32x4 f = __builtin_nontemporal_load((const f32x4*)(Fext + base));
        f32x4 ph, fo;
        #pragma unroll
        for (int k = 0; k < 4; ++k) {
            int comp = (int)((base + k) % 3);
            float dscale = (comp == 2) ? theta_c : u_c;
            float fscale = (comp == 2) ? M_c : F_c;
            ph[k] = p[k] * dscale;
            fo[k] = f[k] / fscale;
        }
        f32x4 zz = (f32x4)0.0f;
        __builtin_nontemporal_store(ph, (f32x4*)(phys + base));
        __builtin_nontemporal_store(fo, (f32x4*)(Fext_nd + base));
        *(f32x4*)(nodal + base) = zz;
    } else {
        for (long i = base; i < n3; ++i) {
            int comp = (int)(i % 3);
            float dscale = (comp == 2) ? theta_c : u_c;
            float fscale = (comp == 2) ? M_c : F_c;
            phys[i] = pred[i] * dscale;
            Fext_nd[i] = Fext[i] / fscale;
            nodal[i] = 0.0f;
        }
    }
}

__global__ void __launch_bounds__(256) beam_elem_kernel(
        const float* __restrict__ pred,
        const float* __restrict__ coords,
        const int*   __restrict__ conn,
        const float* __restrict__ prop_E,
        const float* __restrict__ prop_A,
        const float* __restrict__ prop_I,
        const float* __restrict__ u_c_p,
        const float* __restrict__ theta_c_p,
        const float* __restrict__ F_c_p,
        const float* __restrict__ M_c_p,
        float* __restrict__ nodal,
        float* __restrict__ N_e,
        float* __restrict__ M1_e,
        float* __restrict__ M2_e,
        float* __restrict__ V_e,
        float* __restrict__ l0_o,
        float* __restrict__ c_o,
        float* __restrict__ s_o,
        int n_elems) {
    const float u_c = *u_c_p;
    const float theta_c = *theta_c_p;
    const float F_c = *F_c_p;
    const float M_c = *M_c_p;
    long e = (long)blockIdx.x * blockDim.x + threadIdx.x;
    if (e >= n_elems) return;
    int a = conn[2 * e + 0];
    int b = conn[2 * e + 1];
    float dx0 = coords[3 * b + 0] - coords[3 * a + 0];
    float dz0 = coords[3 * b + 2] - coords[3 * a + 2];
    float l0 = sqrtf(dx0 * dx0 + dz0 * dz0);
    float c = dx0 / l0;
    float s = dz0 / l0;
    float E  = prop_E[e];
    float EA = E * prop_A[e];
    float EI = E * prop_I[e];
    float l0_2 = l0 * l0;
    float l0_3 = l0_2 * l0;
    float k_ax   = EA * u_c     / (F_c * l0);
    float k_bend = EI * theta_c / (M_c * l0);
    float k_sw   = EI * theta_c / (F_c * l0_2);
    float k_tr   = EI * u_c     / (F_c * l0_3);
    float k_mw   = EI * u_c     / (M_c * l0_2);
    float pA0 = pred[3 * a + 0], pA1 = pred[3 * a + 1], pA2 = pred[3 * a + 2];
    float pB0 = pred[3 * b + 0], pB1 = pred[3 * b + 1], pB2 = pred[3 * b + 2];
    float ua =  c * pA0 + s * pA1;
    float wa = -s * pA0 + c * pA1;
    float ta = -pA2;
    float ub =  c * pB0 + s * pB1;
    float wb = -s * pB0 + c * pB1;
    float tb = -pB2;
    float f0 = k_ax * (ua - ub);
    float f1 = 12.0f * k_tr * (wa - wb) + 6.0f * k_sw * (ta + tb);
    float f2 = 6.0f * k_mw * (wa - wb) + k_bend * (4.0f * ta + 2.0f * tb);
    float f5 = 6.0f * k_mw * (wa - wb) + k_bend * (2.0f * ta + 4.0f * tb);
    N_e[e]  = -f0 * F_c;
    M1_e[e] = f2 * M_c;
    M2_e[e] = f5 * M_c;
    V_e[e]  = -f1 * F_c;
    l0_o[e] = l0;
    c_o[e]  = c;
    s_o[e]  = s;
    float gx0 = c * f0 - s * f1;
    float gy0 = s * f0 + c * f1;
    atomic_add_f32(&nodal[3 * a + 0],  gx0);
    atomic_add_f32(&nodal[3 * a + 1],  gy0);
    atomic_add_f32(&nodal[3 * a + 2],  f2);
    atomic_add_f32(&nodal[3 * b + 0], -gx0);
    atomic_add_f32(&nodal[3 * b + 1], -gy0);
    atomic_add_f32(&nodal[3 * b + 2],  f5);
}

extern "C" void kernel_launch(void* const* d_in, const int* in_sizes, int n_in,
                              void* d_out, int out_size, void* d_ws, size_t ws_size,
                              hipStream_t stream) {
    const float* pred    = (const float*)d_in[0];
    const float* coords  = (const float*)d_in[1];
    const int*   conn    = (const int*)  d_in[2];
    const float* prop_E  = (const float*)d_in[3];
    const float* prop_A  = (const float*)d_in[4];
    const float* prop_I  = (const float*)d_in[5];
    const float* Fext    = (const float*)d_in[6];
    const float* u_c_p   = (const float*)d_in[7];
    const float* th_c_p  = (const float*)d_in[8];
    const float* F_c_p   = (const float*)d_in[9];
    const float* M_c_p   = (const float*)d_in[10];

    const int n3      = in_sizes[0];        // N_NODES*3
    const int n_nodes = n3 / 3;
    const int n_elems = in_sizes[3];        // N_ELEMS

    float* out     = (float*)d_out;
    float* nodal   = out;
    float* Fext_nd = nodal + (size_t)n3;
    float* N_e     = Fext_nd + (size_t)n3;
    float* M1_e    = N_e + (size_t)n_elems;
    float* M2_e    = M1_e + (size_t)n_elems;
    float* V_e     = M2_e + (size_t)n_elems;
    float* phys    = V_e + (size_t)n_elems;
    float* l0_o    = phys + (size_t)n3;
    float* c_o     = l0_o + (size_t)n_elems;
    float* s_o     = c_o + (size_t)n_elems;

    const int BLK = 256;

    // ws layout (64B-aligned blocks)
    auto align64 = [](size_t x) { return (x + 63) & ~(size_t)63; };
    size_t off_pk1 = 0;
    size_t off_pk2 = align64(off_pk1 + (size_t)n_nodes * 16);
    size_t off_gx  = align64(off_pk2 + (size_t)n_nodes * 4);
    size_t off_gy  = align64(off_gx  + (size_t)n_elems * 4);
    size_t off_mA  = align64(off_gy  + (size_t)n_elems * 4);
    size_t off_mB  = align64(off_mA  + (size_t)n_elems * 4);
    size_t need    = off_mB + (size_t)n_elems * 4;

    if (ws_size >= need) {
        char* ws = (char*)d_ws;
        f32x4* pk1 = (f32x4*)(ws + off_pk1);
        float* pk2 = (float*)(ws + off_pk2);
        float* gx  = (float*)(ws + off_gx);
        float* gy  = (float*)(ws + off_gy);
        float* mA  = (float*)(ws + off_mA);
        float* mB  = (float*)(ws + off_mB);

        int grid1 = (n_nodes + BLK - 1) / BLK;
        beam_node_pack_kernel<<<grid1, BLK, 0, stream>>>(
            pred, coords, Fext, u_c_p, th_c_p, F_c_p, M_c_p,
            nodal, Fext_nd, phys, pk1, pk2, n_nodes);

        int threads2 = (n_elems + 3) / 4;
        int grid2 = (threads2 + BLK - 1) / BLK;
        beam_elem_compute_kernel<<<grid2, BLK, 0, stream>>>(
            pk1, pk2, conn, prop_E, prop_A, prop_I,
            u_c_p, th_c_p, F_c_p, M_c_p,
            N_e, M1_e, M2_e, V_e, l0_o, c_o, s_o,
            gx, gy, mA, mB, n_elems);

        beam_scatter_kernel<<<grid2, BLK, 0, stream>>>(
            conn, gx, gy, mA, mB, nodal, n_elems);
    } else {
        // Fallback: monolithic path (no workspace)
        int threads1 = (n3 + 3) / 4;
        int grid1 = (threads1 + BLK - 1) / BLK;
        beam_node_kernel<<<grid1, BLK, 0, stream>>>(
            pred, Fext, u_c_p, th_c_p, F_c_p, M_c_p, nodal, Fext_nd, phys, n3);
        int grid2 = (n_elems + BLK - 1) / BLK;
        beam_elem_kernel<<<grid2, BLK, 0, stream>>>(
            pred, coords, conn, prop_E, prop_A, prop_I,
            u_c_p, th_c_p, F_c_p, M_c_p,
            nodal, N_e, M1_e, M2_e, V_e, l0_o, c_o, s_o, n_elems);
    }
}

// Round 5
// 963.205 us; speedup vs baseline: 1.0989x; 1.0989x over previous
//
#include <hip/hip_runtime.h>
#include <hip/hip_bf16.h>

// CorotationalBeam2D: per-element 2D corotational beam forces + nodal scatter.
//
// R4: scatter ablation (R3) showed 18M device-scope fp32 atomics = 880us
// (20.5 G atomic/s, 32B/op write traffic at the coherent point). This round:
// XCD-private accumulator replicas + no-sc1 global_atomic_add_f32 (executes
// at the local XCD L2), then an 8-way reduction. Replica k is only ever
// touched by XCD k (HW_REG_XCC_ID), so the scheme is correct wherever the
// HW performs the RMW; end-of-kernel release makes partials visible.

typedef float f32x4 __attribute__((ext_vector_type(4)));
typedef int   i32x4 __attribute__((ext_vector_type(4)));

#define NUM_XCD 8

__device__ __forceinline__ void atomic_add_dev(float* p, float v) {
#if defined(__gfx90a__) || defined(__gfx940__) || defined(__gfx941__) || defined(__gfx942__) || defined(__gfx950__)
    unsafeAtomicAdd(p, v);   // agent scope (sc1) -> coherent point
#else
    atomicAdd(p, v);
#endif
}

// No-sc-bits fp32 atomic add: performed at the issuing XCD's L2.
// ONLY correct if every atomic to a given address comes from one XCD.
__device__ __forceinline__ void atomic_add_l2(float* p, float v) {
    asm volatile("global_atomic_add_f32 %0, %1, off" :: "v"(p), "v"(v) : "memory");
}

__device__ __forceinline__ int xcc_id() {
    unsigned v;
    asm volatile("s_getreg_b32 %0, hwreg(HW_REG_XCC_ID)" : "=s"(v));
    return (int)(v & (NUM_XCD - 1));
}

// ---------------- K0: zero the replicas ----------------
__global__ void __launch_bounds__(256) zero_kernel(float* __restrict__ p, long n) {
    long stride = (long)gridDim.x * blockDim.x;
    for (long i = (long)blockIdx.x * blockDim.x + threadIdx.x; i * 4 < n; i += stride) {
        long b = i * 4;
        if (b + 4 <= n) {
            *(f32x4*)(p + b) = (f32x4)0.0f;
        } else {
            for (long j = b; j < n; ++j) p[j] = 0.0f;
        }
    }
}

// ---------------- K1: node pass (one thread per node) ----------------
__global__ void __launch_bounds__(256) beam_node_pack_kernel(
        const float* __restrict__ pred,
        const float* __restrict__ coords,
        const float* __restrict__ Fext,
        const float* __restrict__ u_c_p,
        const float* __restrict__ theta_c_p,
        const float* __restrict__ F_c_p,
        const float* __restrict__ M_c_p,
        float* __restrict__ nodal,      // may be null (replica path zeroes via reduce)
        float* __restrict__ Fext_nd,
        float* __restrict__ phys,
        f32x4* __restrict__ pk1,        // {cx, cz, p0, p1}
        float* __restrict__ pk2,        // {p2}
        int n_nodes, int zero_nodal) {
    int n = blockIdx.x * blockDim.x + threadIdx.x;
    if (n >= n_nodes) return;
    const float u_c = *u_c_p;
    const float theta_c = *theta_c_p;
    const float F_c = *F_c_p;
    const float M_c = *M_c_p;

    long b = 3L * n;
    float p0 = pred[b + 0], p1 = pred[b + 1], p2 = pred[b + 2];
    float f0 = Fext[b + 0], f1 = Fext[b + 1], f2 = Fext[b + 2];
    float cx = coords[b + 0];
    float cz = coords[b + 2];

    phys[b + 0] = p0 * u_c;
    phys[b + 1] = p1 * u_c;
    phys[b + 2] = p2 * theta_c;
    Fext_nd[b + 0] = f0 / F_c;
    Fext_nd[b + 1] = f1 / F_c;
    Fext_nd[b + 2] = f2 / M_c;
    if (zero_nodal) {
        nodal[b + 0] = 0.0f;
        nodal[b + 1] = 0.0f;
        nodal[b + 2] = 0.0f;
    }

    f32x4 r; r[0] = cx; r[1] = cz; r[2] = p0; r[3] = p1;
    pk1[n] = r;
    pk2[n] = p2;
}

// ---------------- K2f: fused element compute + XCD-local scatter ----------
__global__ void __launch_bounds__(256) beam_elem_fused_kernel(
        const f32x4* __restrict__ pk1,
        const float* __restrict__ pk2,
        const int*   __restrict__ conn,
        const float* __restrict__ prop_E,
        const float* __restrict__ prop_A,
        const float* __restrict__ prop_I,
        const float* __restrict__ u_c_p,
        const float* __restrict__ theta_c_p,
        const float* __restrict__ F_c_p,
        const float* __restrict__ M_c_p,
        float* __restrict__ N_e,
        float* __restrict__ M1_e,
        float* __restrict__ M2_e,
        float* __restrict__ V_e,
        float* __restrict__ l0_o,
        float* __restrict__ c_o,
        float* __restrict__ s_o,
        float* __restrict__ rep_base,   // NUM_XCD replicas of n3 floats
        long n3,
        int n_elems) {
    const float u_c = *u_c_p;
    const float theta_c = *theta_c_p;
    const float F_c = *F_c_p;
    const float M_c = *M_c_p;

    float* rep = rep_base + (size_t)xcc_id() * n3;

    long t = (long)blockIdx.x * blockDim.x + threadIdx.x;
    long base = t * 4;
    if (base >= n_elems) return;

    if (base + 4 <= n_elems) {
        i32x4 c01 = __builtin_nontemporal_load((const i32x4*)(conn + 2 * base));
        i32x4 c23 = __builtin_nontemporal_load((const i32x4*)(conn + 2 * base + 4));
        f32x4 vE = __builtin_nontemporal_load((const f32x4*)(prop_E + base));
        f32x4 vA = __builtin_nontemporal_load((const f32x4*)(prop_A + base));
        f32x4 vI = __builtin_nontemporal_load((const f32x4*)(prop_I + base));

        int nA[4] = {c01.x, c01.z, c23.x, c23.z};
        int nB[4] = {c01.y, c01.w, c23.y, c23.w};

        f32x4 A1[4], B1[4];
        float A2[4], B2[4];
        #pragma unroll
        for (int k = 0; k < 4; ++k) {
            A1[k] = pk1[nA[k]];
            B1[k] = pk1[nB[k]];
            A2[k] = pk2[nA[k]];
            B2[k] = pk2[nB[k]];
        }

        f32x4 oN, oM1, oM2, oV, oL, oC, oS;
        float fgA0[4], fgA1[4], fgA2[4], fgB2[4];

        #pragma unroll
        for (int k = 0; k < 4; ++k) {
            float dx0 = B1[k][0] - A1[k][0];
            float dz0 = B1[k][1] - A1[k][1];
            float l0 = sqrtf(dx0 * dx0 + dz0 * dz0);
            float c = dx0 / l0;
            float s = dz0 / l0;

            float E  = vE[k];
            float EA = E * vA[k];
            float EI = E * vI[k];

            float l0_2 = l0 * l0;
            float l0_3 = l0_2 * l0;
            float k_ax   = EA * u_c     / (F_c * l0);
            float k_bend = EI * theta_c / (M_c * l0);
            float k_sw   = EI * theta_c / (F_c * l0_2);
            float k_tr   = EI * u_c     / (F_c * l0_3);
            float k_mw   = EI * u_c     / (M_c * l0_2);

            float ua =  c * A1[k][2] + s * A1[k][3];
            float wa = -s * A1[k][2] + c * A1[k][3];
            float ta = -A2[k];
            float ub =  c * B1[k][2] + s * B1[k][3];
            float wb = -s * B1[k][2] + c * B1[k][3];
            float tb = -B2[k];

            float f0 = k_ax * (ua - ub);
            float f1 = 12.0f * k_tr * (wa - wb) + 6.0f * k_sw * (ta + tb);
            float f2 = 6.0f * k_mw * (wa - wb) + k_bend * (4.0f * ta + 2.0f * tb);
            float f5 = 6.0f * k_mw * (wa - wb) + k_bend * (2.0f * ta + 4.0f * tb);

            oN[k]  = -f0 * F_c;          // f3 = -f0 exactly
            oM1[k] = f2 * M_c;
            oM2[k] = f5 * M_c;
            oV[k]  = -f1 * F_c;          // f4 = -f1 exactly
            oL[k]  = l0;
            oC[k]  = c;
            oS[k]  = s;

            fgA0[k] = c * f0 - s * f1;   // fgB0 = -fgA0
            fgA1[k] = s * f0 + c * f1;   // fgB1 = -fgA1
            fgA2[k] = f2;
            fgB2[k] = f5;
        }

        __builtin_nontemporal_store(oN,  (f32x4*)(N_e  + base));
        __builtin_nontemporal_store(oM1, (f32x4*)(M1_e + base));
        __builtin_nontemporal_store(oM2, (f32x4*)(M2_e + base));
        __builtin_nontemporal_store(oV,  (f32x4*)(V_e  + base));
        __builtin_nontemporal_store(oL,  (f32x4*)(l0_o + base));
        __builtin_nontemporal_store(oC,  (f32x4*)(c_o  + base));
        __builtin_nontemporal_store(oS,  (f32x4*)(s_o  + base));

        #pragma unroll
        for (int k = 0; k < 4; ++k) {
            float* pa = rep + 3 * (long)nA[k];
            float* pb = rep + 3 * (long)nB[k];
            atomic_add_l2(pa + 0,  fgA0[k]);
            atomic_add_l2(pa + 1,  fgA1[k]);
            atomic_add_l2(pa + 2,  fgA2[k]);
            atomic_add_l2(pb + 0, -fgA0[k]);
            atomic_add_l2(pb + 1, -fgA1[k]);
            atomic_add_l2(pb + 2,  fgB2[k]);
        }
    } else {
        for (long e = base; e < n_elems; ++e) {
            int a = conn[2 * e + 0];
            int b = conn[2 * e + 1];
            f32x4 A1 = pk1[a], B1 = pk1[b];
            float A2 = pk2[a], B2 = pk2[b];
            float dx0 = B1[0] - A1[0];
            float dz0 = B1[1] - A1[1];
            float l0 = sqrtf(dx0 * dx0 + dz0 * dz0);
            float c = dx0 / l0;
            float s = dz0 / l0;
            float E  = prop_E[e];
            float EA = E * prop_A[e];
            float EI = E * prop_I[e];
            float l0_2 = l0 * l0;
            float l0_3 = l0_2 * l0;
            float k_ax   = EA * u_c     / (F_c * l0);
            float k_bend = EI * theta_c / (M_c * l0);
            float k_sw   = EI * theta_c / (F_c * l0_2);
            float k_tr   = EI * u_c     / (F_c * l0_3);
            float k_mw   = EI * u_c     / (M_c * l0_2);
            float ua =  c * A1[2] + s * A1[3];
            float wa = -s * A1[2] + c * A1[3];
            float ta = -A2;
            float ub =  c * B1[2] + s * B1[3];
            float wb = -s * B1[2] + c * B1[3];
            float tb = -B2;
            float f0 = k_ax * (ua - ub);
            float f1 = 12.0f * k_tr * (wa - wb) + 6.0f * k_sw * (ta + tb);
            float f2 = 6.0f * k_mw * (wa - wb) + k_bend * (4.0f * ta + 2.0f * tb);
            float f5 = 6.0f * k_mw * (wa - wb) + k_bend * (2.0f * ta + 4.0f * tb);
            N_e[e]  = -f0 * F_c;
            M1_e[e] = f2 * M_c;
            M2_e[e] = f5 * M_c;
            V_e[e]  = -f1 * F_c;
            l0_o[e] = l0;
            c_o[e]  = c;
            s_o[e]  = s;
            float gx0 = c * f0 - s * f1;
            float gy0 = s * f0 + c * f1;
            float* pa = rep + 3 * (long)a;
            float* pb = rep + 3 * (long)b;
            atomic_add_l2(pa + 0,  gx0);
            atomic_add_l2(pa + 1,  gy0);
            atomic_add_l2(pa + 2,  f2);
            atomic_add_l2(pb + 0, -gx0);
            atomic_add_l2(pb + 1, -gy0);
            atomic_add_l2(pb + 2,  f5);
        }
    }
}

// ---------------- K3r: reduce 8 replicas -> nodal ----------------
__global__ void __launch_bounds__(256) reduce_kernel(
        const float* __restrict__ rep_base,
        float* __restrict__ nodal,
        long n3) {
    long i = ((long)blockIdx.x * blockDim.x + threadIdx.x) * 4;
    if (i >= n3) return;
    if (i + 4 <= n3) {
        f32x4 acc = (f32x4)0.0f;
        #pragma unroll
        for (int r = 0; r < NUM_XCD; ++r) {
            acc += *(const f32x4*)(rep_base + (size_t)r * n3 + i);
        }
        *(f32x4*)(nodal + i) = acc;
    } else {
        for (long j = i; j < n3; ++j) {
            float acc = 0.0f;
            for (int r = 0; r < NUM_XCD; ++r) acc += rep_base[(size_t)r * n3 + j];
            nodal[j] = acc;
        }
    }
}

// ---------------- Fallback: R3 split K2/K3 + R2 monolithic ----------------
__global__ void __launch_bounds__(256) beam_elem_compute_kernel(
        const f32x4* __restrict__ pk1,
        const float* __restrict__ pk2,
        const int*   __restrict__ conn,
        const float* __restrict__ prop_E,
        const float* __restrict__ prop_A,
        const float* __restrict__ prop_I,
        const float* __restrict__ u_c_p,
        const float* __restrict__ theta_c_p,
        const float* __restrict__ F_c_p,
        const float* __restrict__ M_c_p,
        float* __restrict__ N_e, float* __restrict__ M1_e,
        float* __restrict__ M2_e, float* __restrict__ V_e,
        float* __restrict__ l0_o, float* __restrict__ c_o, float* __restrict__ s_o,
        float* __restrict__ gx, float* __restrict__ gy,
        float* __restrict__ mA, float* __restrict__ mB,
        int n_elems) {
    const float u_c = *u_c_p;
    const float theta_c = *theta_c_p;
    const float F_c = *F_c_p;
    const float M_c = *M_c_p;
    long t = (long)blockIdx.x * blockDim.x + threadIdx.x;
    long base = t * 4;
    if (base >= n_elems) return;
    long lim = (base + 4 <= n_elems) ? base + 4 : n_elems;
    for (long e = base; e < lim; ++e) {
        int a = conn[2 * e + 0];
        int b = conn[2 * e + 1];
        f32x4 A1 = pk1[a], B1 = pk1[b];
        float A2 = pk2[a], B2 = pk2[b];
        float dx0 = B1[0] - A1[0];
        float dz0 = B1[1] - A1[1];
        float l0 = sqrtf(dx0 * dx0 + dz0 * dz0);
        float c = dx0 / l0;
        float s = dz0 / l0;
        float E  = prop_E[e];
        float EA = E * prop_A[e];
        float EI = E * prop_I[e];
        float l0_2 = l0 * l0;
        float l0_3 = l0_2 * l0;
        float k_ax   = EA * u_c     / (F_c * l0);
        float k_bend = EI * theta_c / (M_c * l0);
        float k_sw   = EI * theta_c / (F_c * l0_2);
        float k_tr   = EI * u_c     / (F_c * l0_3);
        float k_mw   = EI * u_c     / (M_c * l0_2);
        float ua =  c * A1[2] + s * A1[3];
        float wa = -s * A1[2] + c * A1[3];
        float ta = -A2;
        float ub =  c * B1[2] + s * B1[3];
        float wb = -s * B1[2] + c * B1[3];
        float tb = -B2;
        float f0 = k_ax * (ua - ub);
        float f1 = 12.0f * k_tr * (wa - wb) + 6.0f * k_sw * (ta + tb);
        float f2 = 6.0f * k_mw * (wa - wb) + k_bend * (4.0f * ta + 2.0f * tb);
        float f5 = 6.0f * k_mw * (wa - wb) + k_bend * (2.0f * ta + 4.0f * tb);
        N_e[e]  = -f0 * F_c;
        M1_e[e] = f2 * M_c;
        M2_e[e] = f5 * M_c;
        V_e[e]  = -f1 * F_c;
        l0_o[e] = l0;
        c_o[e]  = c;
        s_o[e]  = s;
        gx[e] = c * f0 - s * f1;
        gy[e] = s * f0 + c * f1;
        mA[e] = f2;
        mB[e] = f5;
    }
}

__global__ void __launch_bounds__(256) beam_scatter_kernel(
        const int*   __restrict__ conn,
        const float* __restrict__ gx, const float* __restrict__ gy,
        const float* __restrict__ mA, const float* __restrict__ mB,
        float* __restrict__ nodal, int n_elems) {
    long t = (long)blockIdx.x * blockDim.x + threadIdx.x;
    long base = t * 4;
    if (base >= n_elems) return;
    long lim = (base + 4 <= n_elems) ? base + 4 : n_elems;
    for (long e = base; e < lim; ++e) {
        int a = conn[2 * e + 0];
        int b = conn[2 * e + 1];
        float* pa = nodal + 3 * (long)a;
        float* pb = nodal + 3 * (long)b;
        atomic_add_dev(pa + 0,  gx[e]);
        atomic_add_dev(pa + 1,  gy[e]);
        atomic_add_dev(pa + 2,  mA[e]);
        atomic_add_dev(pb + 0, -gx[e]);
        atomic_add_dev(pb + 1, -gy[e]);
        atomic_add_dev(pb + 2,  mB[e]);
    }
}

extern "C" void kernel_launch(void* const* d_in, const int* in_sizes, int n_in,
                              void* d_out, int out_size, void* d_ws, size_t ws_size,
                              hipStream_t stream) {
    const float* pred    = (const float*)d_in[0];
    const float* coords  = (const float*)d_in[1];
    const int*   conn    = (const int*)  d_in[2];
    const float* prop_E  = (const float*)d_in[3];
    const float* prop_A  = (const float*)d_in[4];
    const float* prop_I  = (const float*)d_in[5];
    const float* Fext    = (const float*)d_in[6];
    const float* u_c_p   = (const float*)d_in[7];
    const float* th_c_p  = (const float*)d_in[8];
    const float* F_c_p   = (const float*)d_in[9];
    const float* M_c_p   = (const float*)d_in[10];

    const int n3      = in_sizes[0];        // N_NODES*3
    const int n_nodes = n3 / 3;
    const int n_elems = in_sizes[3];        // N_ELEMS

    float* out     = (float*)d_out;
    float* nodal   = out;
    float* Fext_nd = nodal + (size_t)n3;
    float* N_e     = Fext_nd + (size_t)n3;
    float* M1_e    = N_e + (size_t)n_elems;
    float* M2_e    = M1_e + (size_t)n_elems;
    float* V_e     = M2_e + (size_t)n_elems;
    float* phys    = V_e + (size_t)n_elems;
    float* l0_o    = phys + (size_t)n3;
    float* c_o     = l0_o + (size_t)n_elems;
    float* s_o     = c_o + (size_t)n_elems;

    const int BLK = 256;
    auto align64 = [](size_t x) { return (x + 63) & ~(size_t)63; };

    // Preferred layout: pk1 | pk2 | replicas
    size_t off_pk1 = 0;
    size_t off_pk2 = align64(off_pk1 + (size_t)n_nodes * 16);
    size_t off_rep = align64(off_pk2 + (size_t)n_nodes * 4);
    size_t need_rep = off_rep + (size_t)NUM_XCD * n3 * 4;

    // R3 fallback layout: pk1 | pk2 | gx | gy | mA | mB
    size_t off_gx  = off_rep;
    size_t off_gy  = align64(off_gx + (size_t)n_elems * 4);
    size_t off_mA  = align64(off_gy + (size_t)n_elems * 4);
    size_t off_mB  = align64(off_mA + (size_t)n_elems * 4);
    size_t need_split = off_mB + (size_t)n_elems * 4;

    char* ws = (char*)d_ws;
    int grid_node = (n_nodes + BLK - 1) / BLK;
    int threads_e = (n_elems + 3) / 4;
    int grid_elem = (threads_e + BLK - 1) / BLK;

    if (ws_size >= need_rep) {
        f32x4* pk1 = (f32x4*)(ws + off_pk1);
        float* pk2 = (float*)(ws + off_pk2);
        float* rep = (float*)(ws + off_rep);
        long rep_n = (long)NUM_XCD * n3;

        zero_kernel<<<2048, BLK, 0, stream>>>(rep, rep_n);
        beam_node_pack_kernel<<<grid_node, BLK, 0, stream>>>(
            pred, coords, Fext, u_c_p, th_c_p, F_c_p, M_c_p,
            nullptr, Fext_nd, phys, pk1, pk2, n_nodes, 0);
        beam_elem_fused_kernel<<<grid_elem, BLK, 0, stream>>>(
            pk1, pk2, conn, prop_E, prop_A, prop_I,
            u_c_p, th_c_p, F_c_p, M_c_p,
            N_e, M1_e, M2_e, V_e, l0_o, c_o, s_o,
            rep, (long)n3, n_elems);
        int grid_red = ((n3 + 3) / 4 + BLK - 1) / BLK;
        reduce_kernel<<<grid_red, BLK, 0, stream>>>(rep, nodal, (long)n3);
    } else if (ws_size >= need_split) {
        f32x4* pk1 = (f32x4*)(ws + off_pk1);
        float* pk2 = (float*)(ws + off_pk2);
        float* gx  = (float*)(ws + off_gx);
        float* gy  = (float*)(ws + off_gy);
        float* mA  = (float*)(ws + off_mA);
        float* mB  = (float*)(ws + off_mB);

        beam_node_pack_kernel<<<grid_node, BLK, 0, stream>>>(
            pred, coords, Fext, u_c_p, th_c_p, F_c_p, M_c_p,
            nodal, Fext_nd, phys, pk1, pk2, n_nodes, 1);
        beam_elem_compute_kernel<<<grid_elem, BLK, 0, stream>>>(
            pk1, pk2, conn, prop_E, prop_A, prop_I,
            u_c_p, th_c_p, F_c_p, M_c_p,
            N_e, M1_e, M2_e, V_e, l0_o, c_o, s_o,
            gx, gy, mA, mB, n_elems);
        beam_scatter_kernel<<<grid_elem, BLK, 0, stream>>>(
            conn, gx, gy, mA, mB, nodal, n_elems);
    }
    // (ws_size below need_split is not expected for this problem size)
}

// Round 7
// 345.470 us; speedup vs baseline: 3.0637x; 2.7881x over previous
//
#include <hip/hip_runtime.h>
#include <hip/hip_bf16.h>

// CorotationalBeam2D: per-element 2D corotational beam forces + nodal scatter.
//
// R6: the scatter wall is ~20.5 G atomic TRANSACTIONS/s (R3/R4), payload-
// independent. gfx950 has no packed-f32 atomic (R5 failed to assemble), but
// u64 integer atomicAdd is one transaction. Pack the 3 force components as
// fixed-point fields of one u64: T = qx*2^43 + qy*2^22 + qz (21/21/22-bit
// fields, 8 fraction bits). Integer adds are exact; decode recovers the 3
// sums. Contributions with any |comp| > 64 (handful of tiny-l0 elements)
// escape to a plain f32 (N,3) side accumulator. 18M -> 6M transactions.

typedef float f32x4 __attribute__((ext_vector_type(4)));
typedef int   i32x4 __attribute__((ext_vector_type(4)));

__device__ __forceinline__ void atomic_add_dev(float* p, float v) {
#if defined(__gfx90a__) || defined(__gfx940__) || defined(__gfx941__) || defined(__gfx942__) || defined(__gfx950__)
    unsafeAtomicAdd(p, v);
#else
    atomicAdd(p, v);
#endif
}

#define QSCALE 256.0f          // 8 fraction bits
#define QINV   (1.0f / 256.0f)
#define ESC_TH 64.0f           // escape threshold (value units)

__device__ __forceinline__ unsigned long long pack3(float x, float y, float z) {
    long qx = (long)rintf(x * QSCALE);
    long qy = (long)rintf(y * QSCALE);
    long qz = (long)rintf(z * QSCALE);
    return ((unsigned long long)qx << 43) +
           ((unsigned long long)qy << 22) +
           (unsigned long long)qz;
}

// ---------------- K0: zero a float region ----------------
__global__ void __launch_bounds__(256) zero_kernel(float* __restrict__ p, long n) {
    long stride = (long)gridDim.x * blockDim.x;
    for (long i = (long)blockIdx.x * blockDim.x + threadIdx.x; i * 4 < n; i += stride) {
        long b = i * 4;
        if (b + 4 <= n) {
            *(f32x4*)(p + b) = (f32x4)0.0f;
        } else {
            for (long j = b; j < n; ++j) p[j] = 0.0f;
        }
    }
}

// ---------------- K1: node pass (one thread per node) ----------------
__global__ void __launch_bounds__(256) beam_node_pack_kernel(
        const float* __restrict__ pred,
        const float* __restrict__ coords,
        const float* __restrict__ Fext,
        const float* __restrict__ u_c_p,
        const float* __restrict__ theta_c_p,
        const float* __restrict__ F_c_p,
        const float* __restrict__ M_c_p,
        float* __restrict__ Fext_nd,
        float* __restrict__ phys,
        f32x4* __restrict__ pk1,        // {cx, cz, p0, p1}
        float* __restrict__ pk2,        // {p2}
        int n_nodes) {
    int n = blockIdx.x * blockDim.x + threadIdx.x;
    if (n >= n_nodes) return;
    const float u_c = *u_c_p;
    const float theta_c = *theta_c_p;
    const float F_c = *F_c_p;
    const float M_c = *M_c_p;

    long b = 3L * n;
    float p0 = pred[b + 0], p1 = pred[b + 1], p2 = pred[b + 2];
    float f0 = Fext[b + 0], f1 = Fext[b + 1], f2 = Fext[b + 2];
    float cx = coords[b + 0];
    float cz = coords[b + 2];

    phys[b + 0] = p0 * u_c;
    phys[b + 1] = p1 * u_c;
    phys[b + 2] = p2 * theta_c;
    Fext_nd[b + 0] = f0 / F_c;
    Fext_nd[b + 1] = f1 / F_c;
    Fext_nd[b + 2] = f2 / M_c;

    f32x4 r; r[0] = cx; r[1] = cz; r[2] = p0; r[3] = p1;
    pk1[n] = r;
    pk2[n] = p2;
}

// ---------------- K2: fused element compute + packed-u64 scatter ----------
__global__ void __launch_bounds__(256) beam_elem_fused_kernel(
        const f32x4* __restrict__ pk1,
        const float* __restrict__ pk2,
        const int*   __restrict__ conn,
        const float* __restrict__ prop_E,
        const float* __restrict__ prop_A,
        const float* __restrict__ prop_I,
        const float* __restrict__ u_c_p,
        const float* __restrict__ theta_c_p,
        const float* __restrict__ F_c_p,
        const float* __restrict__ M_c_p,
        float* __restrict__ N_e,
        float* __restrict__ M1_e,
        float* __restrict__ M2_e,
        float* __restrict__ V_e,
        float* __restrict__ l0_o,
        float* __restrict__ c_o,
        float* __restrict__ s_o,
        unsigned long long* __restrict__ acc64,  // (N,) packed accumulator
        float* __restrict__ accf,                // (N,3) escape accumulator
        int n_elems) {
    const float u_c = *u_c_p;
    const float theta_c = *theta_c_p;
    const float F_c = *F_c_p;
    const float M_c = *M_c_p;

    long t = (long)blockIdx.x * blockDim.x + threadIdx.x;
    long base = t * 4;
    if (base >= n_elems) return;

    if (base + 4 <= n_elems) {
        i32x4 c01 = __builtin_nontemporal_load((const i32x4*)(conn + 2 * base));
        i32x4 c23 = __builtin_nontemporal_load((const i32x4*)(conn + 2 * base + 4));
        f32x4 vE = __builtin_nontemporal_load((const f32x4*)(prop_E + base));
        f32x4 vA = __builtin_nontemporal_load((const f32x4*)(prop_A + base));
        f32x4 vI = __builtin_nontemporal_load((const f32x4*)(prop_I + base));

        int nA[4] = {c01.x, c01.z, c23.x, c23.z};
        int nB[4] = {c01.y, c01.w, c23.y, c23.w};

        f32x4 A1[4], B1[4];
        float A2[4], B2[4];
        #pragma unroll
        for (int k = 0; k < 4; ++k) {
            A1[k] = pk1[nA[k]];
            B1[k] = pk1[nB[k]];
            A2[k] = pk2[nA[k]];
            B2[k] = pk2[nB[k]];
        }

        f32x4 oN, oM1, oM2, oV, oL, oC, oS;
        float fgA0[4], fgA1[4], fgA2[4], fgB2[4];

        #pragma unroll
        for (int k = 0; k < 4; ++k) {
            float dx0 = B1[k][0] - A1[k][0];
            float dz0 = B1[k][1] - A1[k][1];
            float l0 = sqrtf(dx0 * dx0 + dz0 * dz0);
            float c = dx0 / l0;
            float s = dz0 / l0;

            float E  = vE[k];
            float EA = E * vA[k];
            float EI = E * vI[k];

            float l0_2 = l0 * l0;
            float l0_3 = l0_2 * l0;
            float k_ax   = EA * u_c     / (F_c * l0);
            float k_bend = EI * theta_c / (M_c * l0);
            float k_sw   = EI * theta_c / (F_c * l0_2);
            float k_tr   = EI * u_c     / (F_c * l0_3);
            float k_mw   = EI * u_c     / (M_c * l0_2);

            float ua =  c * A1[k][2] + s * A1[k][3];
            float wa = -s * A1[k][2] + c * A1[k][3];
            float ta = -A2[k];
            float ub =  c * B1[k][2] + s * B1[k][3];
            float wb = -s * B1[k][2] + c * B1[k][3];
            float tb = -B2[k];

            float f0 = k_ax * (ua - ub);
            float f1 = 12.0f * k_tr * (wa - wb) + 6.0f * k_sw * (ta + tb);
            float f2 = 6.0f * k_mw * (wa - wb) + k_bend * (4.0f * ta + 2.0f * tb);
            float f5 = 6.0f * k_mw * (wa - wb) + k_bend * (2.0f * ta + 4.0f * tb);

            oN[k]  = -f0 * F_c;          // f3 = -f0 exactly
            oM1[k] = f2 * M_c;
            oM2[k] = f5 * M_c;
            oV[k]  = -f1 * F_c;          // f4 = -f1 exactly
            oL[k]  = l0;
            oC[k]  = c;
            oS[k]  = s;

            fgA0[k] = c * f0 - s * f1;   // fgB0 = -fgA0
            fgA1[k] = s * f0 + c * f1;   // fgB1 = -fgA1
            fgA2[k] = f2;
            fgB2[k] = f5;
        }

        __builtin_nontemporal_store(oN,  (f32x4*)(N_e  + base));
        __builtin_nontemporal_store(oM1, (f32x4*)(M1_e + base));
        __builtin_nontemporal_store(oM2, (f32x4*)(M2_e + base));
        __builtin_nontemporal_store(oV,  (f32x4*)(V_e  + base));
        __builtin_nontemporal_store(oL,  (f32x4*)(l0_o + base));
        __builtin_nontemporal_store(oC,  (f32x4*)(c_o  + base));
        __builtin_nontemporal_store(oS,  (f32x4*)(s_o  + base));

        #pragma unroll
        for (int k = 0; k < 4; ++k) {
            float x = fgA0[k], y = fgA1[k], za = fgA2[k], zb = fgB2[k];
            bool esc = (fabsf(x) > ESC_TH) || (fabsf(y) > ESC_TH) ||
                       (fabsf(za) > ESC_TH) || (fabsf(zb) > ESC_TH);
            if (!esc) {
                atomicAdd(&acc64[nA[k]], pack3( x,  y, za));
                atomicAdd(&acc64[nB[k]], pack3(-x, -y, zb));
            } else {
                float* pa = accf + 3 * (long)nA[k];
                float* pb = accf + 3 * (long)nB[k];
                atomic_add_dev(pa + 0,  x);
                atomic_add_dev(pa + 1,  y);
                atomic_add_dev(pa + 2,  za);
                atomic_add_dev(pb + 0, -x);
                atomic_add_dev(pb + 1, -y);
                atomic_add_dev(pb + 2,  zb);
            }
        }
    } else {
        for (long e = base; e < n_elems; ++e) {
            int a = conn[2 * e + 0];
            int b = conn[2 * e + 1];
            f32x4 A1 = pk1[a], B1 = pk1[b];
            float A2 = pk2[a], B2 = pk2[b];
            float dx0 = B1[0] - A1[0];
            float dz0 = B1[1] - A1[1];
            float l0 = sqrtf(dx0 * dx0 + dz0 * dz0);
            float c = dx0 / l0;
            float s = dz0 / l0;
            float E  = prop_E[e];
            float EA = E * prop_A[e];
            float EI = E * prop_I[e];
            float l0_2 = l0 * l0;
            float l0_3 = l0_2 * l0;
            float k_ax   = EA * u_c     / (F_c * l0);
            float k_bend = EI * theta_c / (M_c * l0);
            float k_sw   = EI * theta_c / (F_c * l0_2);
            float k_tr   = EI * u_c     / (F_c * l0_3);
            float k_mw   = EI * u_c     / (M_c * l0_2);
            float ua =  c * A1[2] + s * A1[3];
            float wa = -s * A1[2] + c * A1[3];
            float ta = -A2;
            float ub =  c * B1[2] + s * B1[3];
            float wb = -s * B1[2] + c * B1[3];
            float tb = -B2;
            float f0 = k_ax * (ua - ub);
            float f1 = 12.0f * k_tr * (wa - wb) + 6.0f * k_sw * (ta + tb);
            float f2 = 6.0f * k_mw * (wa - wb) + k_bend * (4.0f * ta + 2.0f * tb);
            float f5 = 6.0f * k_mw * (wa - wb) + k_bend * (2.0f * ta + 4.0f * tb);
            N_e[e]  = -f0 * F_c;
            M1_e[e] = f2 * M_c;
            M2_e[e] = f5 * M_c;
            V_e[e]  = -f1 * F_c;
            l0_o[e] = l0;
            c_o[e]  = c;
            s_o[e]  = s;
            float x = c * f0 - s * f1;
            float y = s * f0 + c * f1;
            bool esc = (fabsf(x) > ESC_TH) || (fabsf(y) > ESC_TH) ||
                       (fabsf(f2) > ESC_TH) || (fabsf(f5) > ESC_TH);
            if (!esc) {
                atomicAdd(&acc64[a], pack3( x,  y, f2));
                atomicAdd(&acc64[b], pack3(-x, -y, f5));
            } else {
                float* pa = accf + 3 * (long)a;
                float* pb = accf + 3 * (long)b;
                atomic_add_dev(pa + 0,  x);
                atomic_add_dev(pa + 1,  y);
                atomic_add_dev(pa + 2,  f2);
                atomic_add_dev(pb + 0, -x);
                atomic_add_dev(pb + 1, -y);
                atomic_add_dev(pb + 2,  f5);
            }
        }
    }
}

// ---------------- K3: decode acc64 + accf -> nodal ----------------
__global__ void __launch_bounds__(256) decode_kernel(
        const unsigned long long* __restrict__ acc64,
        const float* __restrict__ accf,
        float* __restrict__ nodal,
        int n_nodes) {
    int n = blockIdx.x * blockDim.x + threadIdx.x;
    if (n >= n_nodes) return;
    long long T = (long long)acc64[n];
    long long qz = ((long long)((unsigned long long)T << 42)) >> 42;  // low 22b
    T -= qz;
    long long qy = ((long long)((unsigned long long)T << 21)) >> 43;  // bits[22:42]
    T -= (qy << 22);
    long long qx = T >> 43;
    long b = 3L * n;
    nodal[b + 0] = (float)qx * QINV + accf[b + 0];
    nodal[b + 1] = (float)qy * QINV + accf[b + 1];
    nodal[b + 2] = (float)qz * QINV + accf[b + 2];
}

// ---------------- Fallback: monolithic (no workspace) ----------------
__global__ void __launch_bounds__(256) beam_mono_kernel(
        const float* __restrict__ pred,
        const float* __restrict__ coords,
        const int*   __restrict__ conn,
        const float* __restrict__ prop_E,
        const float* __restrict__ prop_A,
        const float* __restrict__ prop_I,
        const float* __restrict__ u_c_p,
        const float* __restrict__ theta_c_p,
        const float* __restrict__ F_c_p,
        const float* __restrict__ M_c_p,
        float* __restrict__ nodal,
        float* __restrict__ N_e, float* __restrict__ M1_e,
        float* __restrict__ M2_e, float* __restrict__ V_e,
        float* __restrict__ l0_o, float* __restrict__ c_o, float* __restrict__ s_o,
        int n_elems) {
    const float u_c = *u_c_p;
    const float theta_c = *theta_c_p;
    const float F_c = *F_c_p;
    const float M_c = *M_c_p;
    long e = (long)blockIdx.x * blockDim.x + threadIdx.x;
    if (e >= n_elems) return;
    int a = conn[2 * e + 0];
    int b = conn[2 * e + 1];
    float dx0 = coords[3 * b + 0] - coords[3 * a + 0];
    float dz0 = coords[3 * b + 2] - coords[3 * a + 2];
    float l0 = sqrtf(dx0 * dx0 + dz0 * dz0);
    float c = dx0 / l0;
    float s = dz0 / l0;
    float E  = prop_E[e];
    float EA = E * prop_A[e];
    float EI = E * prop_I[e];
    float l0_2 = l0 * l0;
    float l0_3 = l0_2 * l0;
    float k_ax   = EA * u_c     / (F_c * l0);
    float k_bend = EI * theta_c / (M_c * l0);
    float k_sw   = EI * theta_c / (F_c * l0_2);
    float k_tr   = EI * u_c     / (F_c * l0_3);
    float k_mw   = EI * u_c     / (M_c * l0_2);
    float pA0 = pred[3 * a + 0], pA1 = pred[3 * a + 1], pA2 = pred[3 * a + 2];
    float pB0 = pred[3 * b + 0], pB1 = pred[3 * b + 1], pB2 = pred[3 * b + 2];
    float ua =  c * pA0 + s * pA1;
    float wa = -s * pA0 + c * pA1;
    float ta = -pA2;
    float ub =  c * pB0 + s * pB1;
    float wb = -s * pB0 + c * pB1;
    float tb = -pB2;
    float f0 = k_ax * (ua - ub);
    float f1 = 12.0f * k_tr * (wa - wb) + 6.0f * k_sw * (ta + tb);
    float f2 = 6.0f * k_mw * (wa - wb) + k_bend * (4.0f * ta + 2.0f * tb);
    float f5 = 6.0f * k_mw * (wa - wb) + k_bend * (2.0f * ta + 4.0f * tb);
    N_e[e]  = -f0 * F_c;
    M1_e[e] = f2 * M_c;
    M2_e[e] = f5 * M_c;
    V_e[e]  = -f1 * F_c;
    l0_o[e] = l0;
    c_o[e]  = c;
    s_o[e]  = s;
    float gx0 = c * f0 - s * f1;
    float gy0 = s * f0 + c * f1;
    atomic_add_dev(&nodal[3 * a + 0],  gx0);
    atomic_add_dev(&nodal[3 * a + 1],  gy0);
    atomic_add_dev(&nodal[3 * a + 2],  f2);
    atomic_add_dev(&nodal[3 * b + 0], -gx0);
    atomic_add_dev(&nodal[3 * b + 1], -gy0);
    atomic_add_dev(&nodal[3 * b + 2],  f5);
}

__global__ void __launch_bounds__(256) beam_node_simple_kernel(
        const float* __restrict__ pred,
        const float* __restrict__ Fext,
        const float* __restrict__ u_c_p,
        const float* __restrict__ theta_c_p,
        const float* __restrict__ F_c_p,
        const float* __restrict__ M_c_p,
        float* __restrict__ nodal,
        float* __restrict__ Fext_nd,
        float* __restrict__ phys,
        int n3) {
    const float u_c = *u_c_p;
    const float theta_c = *theta_c_p;
    const float F_c = *F_c_p;
    const float M_c = *M_c_p;
    long i = (long)blockIdx.x * blockDim.x + threadIdx.x;
    if (i >= n3) return;
    int comp = (int)(i % 3);
    float dscale = (comp == 2) ? theta_c : u_c;
    float fscale = (comp == 2) ? M_c : F_c;
    phys[i] = pred[i] * dscale;
    Fext_nd[i] = Fext[i] / fscale;
    nodal[i] = 0.0f;
}

extern "C" void kernel_launch(void* const* d_in, const int* in_sizes, int n_in,
                              void* d_out, int out_size, void* d_ws, size_t ws_size,
                              hipStream_t stream) {
    const float* pred    = (const float*)d_in[0];
    const float* coords  = (const float*)d_in[1];
    const int*   conn    = (const int*)  d_in[2];
    const float* prop_E  = (const float*)d_in[3];
    const float* prop_A  = (const float*)d_in[4];
    const float* prop_I  = (const float*)d_in[5];
    const float* Fext    = (const float*)d_in[6];
    const float* u_c_p   = (const float*)d_in[7];
    const float* th_c_p  = (const float*)d_in[8];
    const float* F_c_p   = (const float*)d_in[9];
    const float* M_c_p   = (const float*)d_in[10];

    const int n3      = in_sizes[0];        // N_NODES*3
    const int n_nodes = n3 / 3;
    const int n_elems = in_sizes[3];        // N_ELEMS

    float* out     = (float*)d_out;
    float* nodal   = out;
    float* Fext_nd = nodal + (size_t)n3;
    float* N_e     = Fext_nd + (size_t)n3;
    float* M1_e    = N_e + (size_t)n_elems;
    float* M2_e    = M1_e + (size_t)n_elems;
    float* V_e     = M2_e + (size_t)n_elems;
    float* phys    = V_e + (size_t)n_elems;
    float* l0_o    = phys + (size_t)n3;
    float* c_o     = l0_o + (size_t)n_elems;
    float* s_o     = c_o + (size_t)n_elems;

    const int BLK = 256;
    auto align64 = [](size_t x) { return (x + 63) & ~(size_t)63; };

    // ws layout: pk1 | pk2 | acc64 | accf (acc64+accf contiguous for one zero)
    size_t off_pk1 = 0;
    size_t off_pk2 = align64(off_pk1 + (size_t)n_nodes * 16);
    size_t off_a64 = align64(off_pk2 + (size_t)n_nodes * 4);
    size_t off_acf = off_a64 + (size_t)n_nodes * 8;   // contiguous
    size_t need    = off_acf + (size_t)n_nodes * 12;

    char* ws = (char*)d_ws;
    int grid_node = (n_nodes + BLK - 1) / BLK;
    int threads_e = (n_elems + 3) / 4;
    int grid_elem = (threads_e + BLK - 1) / BLK;

    if (ws_size >= need) {
        f32x4* pk1 = (f32x4*)(ws + off_pk1);
        float* pk2 = (float*)(ws + off_pk2);
        unsigned long long* acc64 = (unsigned long long*)(ws + off_a64);
        float* accf = (float*)(ws + off_acf);
        long zero_floats = (long)n_nodes * 5;   // 8B + 12B per node

        zero_kernel<<<2048, BLK, 0, stream>>>((float*)(ws + off_a64), zero_floats);
        beam_node_pack_kernel<<<grid_node, BLK, 0, stream>>>(
            pred, coords, Fext, u_c_p, th_c_p, F_c_p, M_c_p,
            Fext_nd, phys, pk1, pk2, n_nodes);
        beam_elem_fused_kernel<<<grid_elem, BLK, 0, stream>>>(
            pk1, pk2, conn, prop_E, prop_A, prop_I,
            u_c_p, th_c_p, F_c_p, M_c_p,
            N_e, M1_e, M2_e, V_e, l0_o, c_o, s_o,
            acc64, accf, n_elems);
        decode_kernel<<<grid_node, BLK, 0, stream>>>(acc64, accf, nodal, n_nodes);
    } else {
        beam_node_simple_kernel<<<(n3 + BLK - 1) / BLK, BLK, 0, stream>>>(
            pred, Fext, u_c_p, th_c_p, F_c_p, M_c_p, nodal, Fext_nd, phys, n3);
        beam_mono_kernel<<<(n_elems + BLK - 1) / BLK, BLK, 0, stream>>>(
            pred, coords, conn, prop_E, prop_A, prop_I,
            u_c_p, th_c_p, F_c_p, M_c_p,
            nodal, N_e, M1_e, M2_e, V_e, l0_o, c_o, s_o, n_elems);
    }
}

// Round 8
// 328.569 us; speedup vs baseline: 3.2213x; 1.0514x over previous
//
#include <hip/hip_runtime.h>
#include <hip/hip_bf16.h>

// CorotationalBeam2D: per-element 2D corotational beam forces + nodal scatter.
//
// R6 confirmed: scatter wall = ~20.5e9 atomic TRANSACTIONS/s memory-side,
// payload-independent (R3: 18M f32 = 880us; R6: 6M u64 = ~293us). u64
// fixed-point packing (qx<<43 + qy<<22 + qz, 8 fraction bits) carries all 3
// components per transaction; |comp|>64 escapes to f32 side accumulator.
// R7 polish: zeroing fused into node_pack (one less dispatch); atomics
// issued before the streaming stores so the RMW queue drains under them.

typedef float f32x4 __attribute__((ext_vector_type(4)));
typedef int   i32x4 __attribute__((ext_vector_type(4)));

__device__ __forceinline__ void atomic_add_dev(float* p, float v) {
#if defined(__gfx90a__) || defined(__gfx940__) || defined(__gfx941__) || defined(__gfx942__) || defined(__gfx950__)
    unsafeAtomicAdd(p, v);
#else
    atomicAdd(p, v);
#endif
}

#define QSCALE 256.0f          // 8 fraction bits
#define QINV   (1.0f / 256.0f)
#define ESC_TH 64.0f           // escape threshold (value units)

__device__ __forceinline__ unsigned long long pack3(float x, float y, float z) {
    long qx = (long)rintf(x * QSCALE);
    long qy = (long)rintf(y * QSCALE);
    long qz = (long)rintf(z * QSCALE);
    return ((unsigned long long)qx << 43) +
           ((unsigned long long)qy << 22) +
           (unsigned long long)qz;
}

// ---------------- K1: node pass (one thread per node) ----------------
// Also zeroes the packed + escape accumulators (same node domain).
__global__ void __launch_bounds__(256) beam_node_pack_kernel(
        const float* __restrict__ pred,
        const float* __restrict__ coords,
        const float* __restrict__ Fext,
        const float* __restrict__ u_c_p,
        const float* __restrict__ theta_c_p,
        const float* __restrict__ F_c_p,
        const float* __restrict__ M_c_p,
        float* __restrict__ Fext_nd,
        float* __restrict__ phys,
        f32x4* __restrict__ pk1,        // {cx, cz, p0, p1}
        float* __restrict__ pk2,        // {p2}
        unsigned long long* __restrict__ acc64,
        float* __restrict__ accf,
        int n_nodes) {
    int n = blockIdx.x * blockDim.x + threadIdx.x;
    if (n >= n_nodes) return;
    const float u_c = *u_c_p;
    const float theta_c = *theta_c_p;
    const float F_c = *F_c_p;
    const float M_c = *M_c_p;

    long b = 3L * n;
    float p0 = pred[b + 0], p1 = pred[b + 1], p2 = pred[b + 2];
    float f0 = Fext[b + 0], f1 = Fext[b + 1], f2 = Fext[b + 2];
    float cx = coords[b + 0];
    float cz = coords[b + 2];

    phys[b + 0] = p0 * u_c;
    phys[b + 1] = p1 * u_c;
    phys[b + 2] = p2 * theta_c;
    Fext_nd[b + 0] = f0 / F_c;
    Fext_nd[b + 1] = f1 / F_c;
    Fext_nd[b + 2] = f2 / M_c;

    f32x4 r; r[0] = cx; r[1] = cz; r[2] = p0; r[3] = p1;
    pk1[n] = r;
    pk2[n] = p2;

    acc64[n] = 0ull;
    accf[b + 0] = 0.0f;
    accf[b + 1] = 0.0f;
    accf[b + 2] = 0.0f;
}

// ---------------- K2: fused element compute + packed-u64 scatter ----------
__global__ void __launch_bounds__(256) beam_elem_fused_kernel(
        const f32x4* __restrict__ pk1,
        const float* __restrict__ pk2,
        const int*   __restrict__ conn,
        const float* __restrict__ prop_E,
        const float* __restrict__ prop_A,
        const float* __restrict__ prop_I,
        const float* __restrict__ u_c_p,
        const float* __restrict__ theta_c_p,
        const float* __restrict__ F_c_p,
        const float* __restrict__ M_c_p,
        float* __restrict__ N_e,
        float* __restrict__ M1_e,
        float* __restrict__ M2_e,
        float* __restrict__ V_e,
        float* __restrict__ l0_o,
        float* __restrict__ c_o,
        float* __restrict__ s_o,
        unsigned long long* __restrict__ acc64,  // (N,) packed accumulator
        float* __restrict__ accf,                // (N,3) escape accumulator
        int n_elems) {
    const float u_c = *u_c_p;
    const float theta_c = *theta_c_p;
    const float F_c = *F_c_p;
    const float M_c = *M_c_p;

    long t = (long)blockIdx.x * blockDim.x + threadIdx.x;
    long base = t * 4;
    if (base >= n_elems) return;

    if (base + 4 <= n_elems) {
        i32x4 c01 = __builtin_nontemporal_load((const i32x4*)(conn + 2 * base));
        i32x4 c23 = __builtin_nontemporal_load((const i32x4*)(conn + 2 * base + 4));
        f32x4 vE = __builtin_nontemporal_load((const f32x4*)(prop_E + base));
        f32x4 vA = __builtin_nontemporal_load((const f32x4*)(prop_A + base));
        f32x4 vI = __builtin_nontemporal_load((const f32x4*)(prop_I + base));

        int nA[4] = {c01.x, c01.z, c23.x, c23.z};
        int nB[4] = {c01.y, c01.w, c23.y, c23.w};

        f32x4 A1[4], B1[4];
        float A2[4], B2[4];
        #pragma unroll
        for (int k = 0; k < 4; ++k) {
            A1[k] = pk1[nA[k]];
            B1[k] = pk1[nB[k]];
            A2[k] = pk2[nA[k]];
            B2[k] = pk2[nB[k]];
        }

        f32x4 oN, oM1, oM2, oV, oL, oC, oS;
        float fgA0[4], fgA1[4], fgA2[4], fgB2[4];

        #pragma unroll
        for (int k = 0; k < 4; ++k) {
            float dx0 = B1[k][0] - A1[k][0];
            float dz0 = B1[k][1] - A1[k][1];
            float l0 = sqrtf(dx0 * dx0 + dz0 * dz0);
            float c = dx0 / l0;
            float s = dz0 / l0;

            float E  = vE[k];
            float EA = E * vA[k];
            float EI = E * vI[k];

            float l0_2 = l0 * l0;
            float l0_3 = l0_2 * l0;
            float k_ax   = EA * u_c     / (F_c * l0);
            float k_bend = EI * theta_c / (M_c * l0);
            float k_sw   = EI * theta_c / (F_c * l0_2);
            float k_tr   = EI * u_c     / (F_c * l0_3);
            float k_mw   = EI * u_c     / (M_c * l0_2);

            float ua =  c * A1[k][2] + s * A1[k][3];
            float wa = -s * A1[k][2] + c * A1[k][3];
            float ta = -A2[k];
            float ub =  c * B1[k][2] + s * B1[k][3];
            float wb = -s * B1[k][2] + c * B1[k][3];
            float tb = -B2[k];

            float f0 = k_ax * (ua - ub);
            float f1 = 12.0f * k_tr * (wa - wb) + 6.0f * k_sw * (ta + tb);
            float f2 = 6.0f * k_mw * (wa - wb) + k_bend * (4.0f * ta + 2.0f * tb);
            float f5 = 6.0f * k_mw * (wa - wb) + k_bend * (2.0f * ta + 4.0f * tb);

            oN[k]  = -f0 * F_c;          // f3 = -f0 exactly
            oM1[k] = f2 * M_c;
            oM2[k] = f5 * M_c;
            oV[k]  = -f1 * F_c;          // f4 = -f1 exactly
            oL[k]  = l0;
            oC[k]  = c;
            oS[k]  = s;

            fgA0[k] = c * f0 - s * f1;   // fgB0 = -fgA0
            fgA1[k] = s * f0 + c * f1;   // fgB1 = -fgA1
            fgA2[k] = f2;
            fgB2[k] = f5;
        }

        // atomics first: the memory-side RMW queue drains under the stores
        #pragma unroll
        for (int k = 0; k < 4; ++k) {
            float x = fgA0[k], y = fgA1[k], za = fgA2[k], zb = fgB2[k];
            bool esc = (fabsf(x) > ESC_TH) || (fabsf(y) > ESC_TH) ||
                       (fabsf(za) > ESC_TH) || (fabsf(zb) > ESC_TH);
            if (!esc) {
                atomicAdd(&acc64[nA[k]], pack3( x,  y, za));
                atomicAdd(&acc64[nB[k]], pack3(-x, -y, zb));
            } else {
                float* pa = accf + 3 * (long)nA[k];
                float* pb = accf + 3 * (long)nB[k];
                atomic_add_dev(pa + 0,  x);
                atomic_add_dev(pa + 1,  y);
                atomic_add_dev(pa + 2,  za);
                atomic_add_dev(pb + 0, -x);
                atomic_add_dev(pb + 1, -y);
                atomic_add_dev(pb + 2,  zb);
            }
        }

        __builtin_nontemporal_store(oN,  (f32x4*)(N_e  + base));
        __builtin_nontemporal_store(oM1, (f32x4*)(M1_e + base));
        __builtin_nontemporal_store(oM2, (f32x4*)(M2_e + base));
        __builtin_nontemporal_store(oV,  (f32x4*)(V_e  + base));
        __builtin_nontemporal_store(oL,  (f32x4*)(l0_o + base));
        __builtin_nontemporal_store(oC,  (f32x4*)(c_o  + base));
        __builtin_nontemporal_store(oS,  (f32x4*)(s_o  + base));
    } else {
        for (long e = base; e < n_elems; ++e) {
            int a = conn[2 * e + 0];
            int b = conn[2 * e + 1];
            f32x4 A1 = pk1[a], B1 = pk1[b];
            float A2 = pk2[a], B2 = pk2[b];
            float dx0 = B1[0] - A1[0];
            float dz0 = B1[1] - A1[1];
            float l0 = sqrtf(dx0 * dx0 + dz0 * dz0);
            float c = dx0 / l0;
            float s = dz0 / l0;
            float E  = prop_E[e];
            float EA = E * prop_A[e];
            float EI = E * prop_I[e];
            float l0_2 = l0 * l0;
            float l0_3 = l0_2 * l0;
            float k_ax   = EA * u_c     / (F_c * l0);
            float k_bend = EI * theta_c / (M_c * l0);
            float k_sw   = EI * theta_c / (F_c * l0_2);
            float k_tr   = EI * u_c     / (F_c * l0_3);
            float k_mw   = EI * u_c     / (M_c * l0_2);
            float ua =  c * A1[2] + s * A1[3];
            float wa = -s * A1[2] + c * A1[3];
            float ta = -A2;
            float ub =  c * B1[2] + s * B1[3];
            float wb = -s * B1[2] + c * B1[3];
            float tb = -B2;
            float f0 = k_ax * (ua - ub);
            float f1 = 12.0f * k_tr * (wa - wb) + 6.0f * k_sw * (ta + tb);
            float f2 = 6.0f * k_mw * (wa - wb) + k_bend * (4.0f * ta + 2.0f * tb);
            float f5 = 6.0f * k_mw * (wa - wb) + k_bend * (2.0f * ta + 4.0f * tb);
            N_e[e]  = -f0 * F_c;
            M1_e[e] = f2 * M_c;
            M2_e[e] = f5 * M_c;
            V_e[e]  = -f1 * F_c;
            l0_o[e] = l0;
            c_o[e]  = c;
            s_o[e]  = s;
            float x = c * f0 - s * f1;
            float y = s * f0 + c * f1;
            bool esc = (fabsf(x) > ESC_TH) || (fabsf(y) > ESC_TH) ||
                       (fabsf(f2) > ESC_TH) || (fabsf(f5) > ESC_TH);
            if (!esc) {
                atomicAdd(&acc64[a], pack3( x,  y, f2));
                atomicAdd(&acc64[b], pack3(-x, -y, f5));
            } else {
                float* pa = accf + 3 * (long)a;
                float* pb = accf + 3 * (long)b;
                atomic_add_dev(pa + 0,  x);
                atomic_add_dev(pa + 1,  y);
                atomic_add_dev(pa + 2,  f2);
                atomic_add_dev(pb + 0, -x);
                atomic_add_dev(pb + 1, -y);
                atomic_add_dev(pb + 2,  f5);
            }
        }
    }
}

// ---------------- K3: decode acc64 + accf -> nodal ----------------
__global__ void __launch_bounds__(256) decode_kernel(
        const unsigned long long* __restrict__ acc64,
        const float* __restrict__ accf,
        float* __restrict__ nodal,
        int n_nodes) {
    int n = blockIdx.x * blockDim.x + threadIdx.x;
    if (n >= n_nodes) return;
    long long T = (long long)acc64[n];
    long long qz = ((long long)((unsigned long long)T << 42)) >> 42;  // low 22b
    T -= qz;
    long long qy = ((long long)((unsigned long long)T << 21)) >> 43;  // bits[22:42]
    T -= (qy << 22);
    long long qx = T >> 43;
    long b = 3L * n;
    nodal[b + 0] = (float)qx * QINV + accf[b + 0];
    nodal[b + 1] = (float)qy * QINV + accf[b + 1];
    nodal[b + 2] = (float)qz * QINV + accf[b + 2];
}

// ---------------- Fallback: monolithic (no workspace) ----------------
__global__ void __launch_bounds__(256) beam_mono_kernel(
        const float* __restrict__ pred,
        const float* __restrict__ coords,
        const int*   __restrict__ conn,
        const float* __restrict__ prop_E,
        const float* __restrict__ prop_A,
        const float* __restrict__ prop_I,
        const float* __restrict__ u_c_p,
        const float* __restrict__ theta_c_p,
        const float* __restrict__ F_c_p,
        const float* __restrict__ M_c_p,
        float* __restrict__ nodal,
        float* __restrict__ N_e, float* __restrict__ M1_e,
        float* __restrict__ M2_e, float* __restrict__ V_e,
        float* __restrict__ l0_o, float* __restrict__ c_o, float* __restrict__ s_o,
        int n_elems) {
    const float u_c = *u_c_p;
    const float theta_c = *theta_c_p;
    const float F_c = *F_c_p;
    const float M_c = *M_c_p;
    long e = (long)blockIdx.x * blockDim.x + threadIdx.x;
    if (e >= n_elems) return;
    int a = conn[2 * e + 0];
    int b = conn[2 * e + 1];
    float dx0 = coords[3 * b + 0] - coords[3 * a + 0];
    float dz0 = coords[3 * b + 2] - coords[3 * a + 2];
    float l0 = sqrtf(dx0 * dx0 + dz0 * dz0);
    float c = dx0 / l0;
    float s = dz0 / l0;
    float E  = prop_E[e];
    float EA = E * prop_A[e];
    float EI = E * prop_I[e];
    float l0_2 = l0 * l0;
    float l0_3 = l0_2 * l0;
    float k_ax   = EA * u_c     / (F_c * l0);
    float k_bend = EI * theta_c / (M_c * l0);
    float k_sw   = EI * theta_c / (F_c * l0_2);
    float k_tr   = EI * u_c     / (F_c * l0_3);
    float k_mw   = EI * u_c     / (M_c * l0_2);
    float pA0 = pred[3 * a + 0], pA1 = pred[3 * a + 1], pA2 = pred[3 * a + 2];
    float pB0 = pred[3 * b + 0], pB1 = pred[3 * b + 1], pB2 = pred[3 * b + 2];
    float ua =  c * pA0 + s * pA1;
    float wa = -s * pA0 + c * pA1;
    float ta = -pA2;
    float ub =  c * pB0 + s * pB1;
    float wb = -s * pB0 + c * pB1;
    float tb = -pB2;
    float f0 = k_ax * (ua - ub);
    float f1 = 12.0f * k_tr * (wa - wb) + 6.0f * k_sw * (ta + tb);
    float f2 = 6.0f * k_mw * (wa - wb) + k_bend * (4.0f * ta + 2.0f * tb);
    float f5 = 6.0f * k_mw * (wa - wb) + k_bend * (2.0f * ta + 4.0f * tb);
    N_e[e]  = -f0 * F_c;
    M1_e[e] = f2 * M_c;
    M2_e[e] = f5 * M_c;
    V_e[e]  = -f1 * F_c;
    l0_o[e] = l0;
    c_o[e]  = c;
    s_o[e]  = s;
    float gx0 = c * f0 - s * f1;
    float gy0 = s * f0 + c * f1;
    atomic_add_dev(&nodal[3 * a + 0],  gx0);
    atomic_add_dev(&nodal[3 * a + 1],  gy0);
    atomic_add_dev(&nodal[3 * a + 2],  f2);
    atomic_add_dev(&nodal[3 * b + 0], -gx0);
    atomic_add_dev(&nodal[3 * b + 1], -gy0);
    atomic_add_dev(&nodal[3 * b + 2],  f5);
}

__global__ void __launch_bounds__(256) beam_node_simple_kernel(
        const float* __restrict__ pred,
        const float* __restrict__ Fext,
        const float* __restrict__ u_c_p,
        const float* __restrict__ theta_c_p,
        const float* __restrict__ F_c_p,
        const float* __restrict__ M_c_p,
        float* __restrict__ nodal,
        float* __restrict__ Fext_nd,
        float* __restrict__ phys,
        int n3) {
    const float u_c = *u_c_p;
    const float theta_c = *theta_c_p;
    const float F_c = *F_c_p;
    const float M_c = *M_c_p;
    long i = (long)blockIdx.x * blockDim.x + threadIdx.x;
    if (i >= n3) return;
    int comp = (int)(i % 3);
    float dscale = (comp == 2) ? theta_c : u_c;
    float fscale = (comp == 2) ? M_c : F_c;
    phys[i] = pred[i] * dscale;
    Fext_nd[i] = Fext[i] / fscale;
    nodal[i] = 0.0f;
}

extern "C" void kernel_launch(void* const* d_in, const int* in_sizes, int n_in,
                              void* d_out, int out_size, void* d_ws, size_t ws_size,
                              hipStream_t stream) {
    const float* pred    = (const float*)d_in[0];
    const float* coords  = (const float*)d_in[1];
    const int*   conn    = (const int*)  d_in[2];
    const float* prop_E  = (const float*)d_in[3];
    const float* prop_A  = (const float*)d_in[4];
    const float* prop_I  = (const float*)d_in[5];
    const float* Fext    = (const float*)d_in[6];
    const float* u_c_p   = (const float*)d_in[7];
    const float* th_c_p  = (const float*)d_in[8];
    const float* F_c_p   = (const float*)d_in[9];
    const float* M_c_p   = (const float*)d_in[10];

    const int n3      = in_sizes[0];        // N_NODES*3
    const int n_nodes = n3 / 3;
    const int n_elems = in_sizes[3];        // N_ELEMS

    float* out     = (float*)d_out;
    float* nodal   = out;
    float* Fext_nd = nodal + (size_t)n3;
    float* N_e     = Fext_nd + (size_t)n3;
    float* M1_e    = N_e + (size_t)n_elems;
    float* M2_e    = M1_e + (size_t)n_elems;
    float* V_e     = M2_e + (size_t)n_elems;
    float* phys    = V_e + (size_t)n_elems;
    float* l0_o    = phys + (size_t)n3;
    float* c_o     = l0_o + (size_t)n_elems;
    float* s_o     = c_o + (size_t)n_elems;

    const int BLK = 256;
    auto align64 = [](size_t x) { return (x + 63) & ~(size_t)63; };

    // ws layout: pk1 | pk2 | acc64 | accf
    size_t off_pk1 = 0;
    size_t off_pk2 = align64(off_pk1 + (size_t)n_nodes * 16);
    size_t off_a64 = align64(off_pk2 + (size_t)n_nodes * 4);
    size_t off_acf = off_a64 + (size_t)n_nodes * 8;
    size_t need    = off_acf + (size_t)n_nodes * 12;

    char* ws = (char*)d_ws;
    int grid_node = (n_nodes + BLK - 1) / BLK;
    int threads_e = (n_elems + 3) / 4;
    int grid_elem = (threads_e + BLK - 1) / BLK;

    if (ws_size >= need) {
        f32x4* pk1 = (f32x4*)(ws + off_pk1);
        float* pk2 = (float*)(ws + off_pk2);
        unsigned long long* acc64 = (unsigned long long*)(ws + off_a64);
        float* accf = (float*)(ws + off_acf);

        beam_node_pack_kernel<<<grid_node, BLK, 0, stream>>>(
            pred, coords, Fext, u_c_p, th_c_p, F_c_p, M_c_p,
            Fext_nd, phys, pk1, pk2, acc64, accf, n_nodes);
        beam_elem_fused_kernel<<<grid_elem, BLK, 0, stream>>>(
            pk1, pk2, conn, prop_E, prop_A, prop_I,
            u_c_p, th_c_p, F_c_p, M_c_p,
            N_e, M1_e, M2_e, V_e, l0_o, c_o, s_o,
            acc64, accf, n_elems);
        decode_kernel<<<grid_node, BLK, 0, stream>>>(acc64, accf, nodal, n_nodes);
    } else {
        beam_node_simple_kernel<<<(n3 + BLK - 1) / BLK, BLK, 0, stream>>>(
            pred, Fext, u_c_p, th_c_p, F_c_p, M_c_p, nodal, Fext_nd, phys, n3);
        beam_mono_kernel<<<(n_elems + BLK - 1) / BLK, BLK, 0, stream>>>(
            pred, coords, conn, prop_E, prop_A, prop_I,
            u_c_p, th_c_p, F_c_p, M_c_p,
            nodal, N_e, M1_e, M2_e, V_e, l0_o, c_o, s_o, n_elems);
    }
}